// Round 15
// baseline (366.914 us; speedup 1.0000x reference)
//
#include <hip/hip_runtime.h>
#include <math.h>

#define BB 512
#define TT 49
#define VV 34
#define FF 16
#define HH 64
#define WW 46
#define BW (BB*WW)        /* 23552 */
#define TH3 (3*HH)        /* 192 */
#define ROWS 25088        /* B*T */

/* GRU-region (offsets in floats) */
#define SOUT_OFF   0ull
#define XW1_OFF    376832ull              /* BW*192 */
#define G1_OFF     (XW1_OFF + 4521984ull)
#define XW2_OFF    (G1_OFF + 1507328ull)
#define G2_OFF     (XW2_OFF + 4521984ull) /* ends 12435456 */

#define MSG_SZ     12812288ull            /* B*V*W*F */
#define CUM_SZ     852992ull              /* B*T*V */
#define MEANS_SZ   17408ull               /* B*V */
#define AO_OFF     12435456ull
#define MSG2_OFF   (AO_OFF + MSG_SZ)      /* 25247744 */
#define CUM2_OFF   (MSG2_OFF + MSG_SZ)
#define LAST2_OFF  (CUM2_OFF + CUM_SZ)
#define MEANS2_OFF (LAST2_OFF + CUM_SZ)
#define MAX2_OFF   (MEANS2_OFF + MEANS_SZ)
#define PQ_OFF     (MAX2_OFF + 4ull)
#define SAW_OFF    (PQ_OFF + 6528ull)
#define FW_OFF     (SAW_OFF + 292ull)     /* 34*816 = 27744 */
#define WVIH_OFF   (FW_OFF + 27744ull)    /* 16*192 = 3072 */
#define BIAS2_OFF  (WVIH_OFF + 3072ull)   /* 192 */

#define RL(x,i) __uint_as_float(__builtin_amdgcn_readlane(__float_as_uint(x), (i)))
__device__ __forceinline__ float fsig(float x) { return 1.f / (1.f + __expf(-x)); }
__device__ __forceinline__ float ftanh(float x) {
  float t = __expf(2.f * x);
  return 1.f - 2.f / (t + 1.f);
}

/* ---------------- kernel 1: impute scan + global max + means ---------------- */
__global__ __launch_bounds__(256) void k_scan(
    const float* __restrict__ arr, const float* __restrict__ msk,
    const float* __restrict__ timeTB,
    float* __restrict__ cum, float* __restrict__ last,
    float* __restrict__ means, unsigned int* __restrict__ maxv) {
  int tid = blockIdx.x * 256 + threadIdx.x;     /* 0..17407, exact */
  int b = tid / VV, v = tid - b * VV;
  const int base = b * TT * VV + v;
  float x = arr[base];
  float c = 0.f, lm = 0.f, s = x;
  cum[base] = 0.f;
  last[base] = x;
  float tp = timeTB[b];
  for (int t = 1; t < TT; ++t) {
    float tc = timeTB[t * BB + b];
    float d = tc - tp; tp = tc;
    int e = base + t * VV;
    float a = arr[e], m = msk[e];
    float miss = (m == 0.f) ? 1.f : 0.f;
    c = d + c * miss;
    x = (miss > 0.f) ? x : a;
    cum[e] = c; last[e] = x;
    lm = fmaxf(lm, c);
    s += a;
  }
  means[tid] = s * (1.f / 49.f);
  #pragma unroll
  for (int off = 32; off; off >>= 1) lm = fmaxf(lm, __shfl_xor(lm, off));
  if ((threadIdx.x & 63) == 0) atomicMax(maxv, __float_as_uint(lm));
}

/* ---------------- prep: PE proj + SA bilinear + weight folds ---------------- */
__global__ __launch_bounds__(256) void k_prep(
    const float* __restrict__ tlaWq, const float* __restrict__ tlaWk,
    const float* __restrict__ tlaWv,
    const float* __restrict__ tlaBq, const float* __restrict__ tlaBk,
    const float* __restrict__ tlaBv,
    const float* __restrict__ saWq, const float* __restrict__ saBq,
    const float* __restrict__ saWk, const float* __restrict__ saBk,
    const float* __restrict__ saWv, const float* __restrict__ saBv,
    const float* __restrict__ encW2, const float* __restrict__ encB2,
    const float* __restrict__ Wih0, const float* __restrict__ bih0,
    float* __restrict__ pqg, float* __restrict__ saw, float* __restrict__ fw,
    float* __restrict__ wvih, float* __restrict__ bias2) {
  const int bid = blockIdx.x;
  const int t = threadIdx.x;
  if (bid < 26) {
    int idx = bid * 256 + t;
    if (idx >= 6528) return;
    int which = idx / 2176;
    int r = idx - which * 2176;
    int l = r / 544;
    int rr = r - l * 544;
    int v = rr >> 4, f = rr & 15;
    const float* W = which == 0 ? tlaWq : which == 1 ? tlaWk : tlaWv;
    float acc = 0.f;
    #pragma unroll
    for (int i = 0; i < FF; ++i) {
      int i2 = i & ~1;
      float dv = expf(-logf(10000.f) * (float)i2 / (float)FF);
      float ang = (float)l * dv;
      float pe = (i & 1) ? cosf(ang) : sinf(ang);
      acc += pe * W[v * 256 + i * 16 + f];
    }
    pqg[idx] = acc;
  } else if (bid == 26) {
    int i = t & 15, j = t >> 4;
    float a = 0.f;
    #pragma unroll
    for (int f = 0; f < 16; ++f) a += saWq[i * 16 + f] * saWk[j * 16 + f];
    saw[j * 16 + i] = a;                    /* A[i][j] at [j*16+i] */
    if (t < 16) {
      float pp = 0.f, qq = 0.f;
      #pragma unroll
      for (int f = 0; f < 16; ++f) { pp += saWq[t * 16 + f] * saBk[f]; qq += saWk[t * 16 + f] * saBq[f]; }
      saw[256 + t] = pp;
      saw[272 + t] = qq;
    }
    if (t == 0) {
      float c = 0.f;
      #pragma unroll
      for (int f = 0; f < 16; ++f) c += saBq[f] * saBk[f];
      saw[288] = c;
    }
  } else if (bid < 61) {
    const int v = bid - 27;
    const int f = t >> 4, o = t & 15;
    const float* W2v = encW2 + v * 256;
    float cq = 0.f, ck = 0.f, cv = 0.f;
    #pragma unroll
    for (int g = 0; g < 16; ++g) {
      float w2 = W2v[f * 16 + g];
      cq += w2 * tlaWq[v * 256 + g * 16 + o];
      ck += w2 * tlaWk[v * 256 + g * 16 + o];
      cv += w2 * tlaWv[v * 256 + g * 16 + o];
    }
    fw[v * 816 + 0 * 272 + f * 16 + o] = cq;
    fw[v * 816 + 1 * 272 + f * 16 + o] = ck;
    fw[v * 816 + 2 * 272 + f * 16 + o] = cv;
    if (t < 48) {
      int which = t >> 4, o2 = t & 15;
      const float* Wp = which == 0 ? tlaWq : which == 1 ? tlaWk : tlaWv;
      const float* Bp = which == 0 ? tlaBq : which == 1 ? tlaBk : tlaBv;
      float acc = Bp[v * 16 + o2];
      #pragma unroll
      for (int g = 0; g < 16; ++g) acc += encB2[v * 16 + g] * Wp[v * 256 + g * 16 + o2];
      fw[v * 816 + which * 272 + 256 + o2] = acc;
    }
  } else if (bid < 73) {
    int idx = (bid - 61) * 256 + t;          /* < 3072 exact */
    int i = idx / 192, o = idx - i * 192;
    float acc = 0.f;
    #pragma unroll
    for (int f = 0; f < 16; ++f) acc += saWv[i * 16 + f] * Wih0[f * 192 + o];
    wvih[idx] = acc;
  } else {
    if (t < 192) {
      float acc = bih0[t];
      #pragma unroll
      for (int f = 0; f < 16; ++f) acc += 34.f * saBv[f] * Wih0[f * 192 + t];
      bias2[t] = acc;
    }
  }
}

/* ------- fused impute + MLP + folded QKV proj + windowed 4x4 attention -------
   round-9 version: pkv stride 17 (odd -> conflict-free scalar access) */
__global__ __launch_bounds__(256) void k_enc4(
    const float* __restrict__ arr, const float* __restrict__ msk,
    const float* __restrict__ cum, const float* __restrict__ last,
    const float* __restrict__ means, const unsigned int* __restrict__ maxv,
    const float* __restrict__ wdec, const float* __restrict__ bdec,
    const float* __restrict__ W1, const float* __restrict__ B1,
    const float* __restrict__ fw, const float* __restrict__ pqg,
    float* __restrict__ ao) {
  __shared__ float pkv[4][3][TT * 17];
  const int v = blockIdx.x % VV;
  const int bgrp = blockIdx.x / VV;        /* grid = 34*128 */
  const int tid = threadIdx.x;
  const int wave = tid >> 6, lane = tid & 63;
  const int b = bgrp * 4 + wave;
  const float* fv = fw + v * 816;
  if (lane < TT) {
    const int t = lane;
    const int idx = (b * TT + t) * VV + v;
    float inv = 1.f / __uint_as_float(*maxv);
    float a = arr[idx], m = msk[idx];
    float cc = cum[idx] * inv;
    float ttc = fminf(fmaxf(wdec[v] * cc + bdec[v], 0.f), 1000.f);
    float dec = expf(-ttc);
    float xx = a * m + (1.f - m) * (dec * last[idx] + (1.f - dec) * means[b * VV + v]);
    float h[16];
    #pragma unroll
    for (int f = 0; f < 16; ++f)
      h[f] = fmaxf(xx * W1[v * 32 + f] + m * W1[v * 32 + 16 + f] + B1[v * 16 + f], 0.f);
    #pragma unroll
    for (int which = 0; which < 3; ++which) {
      const float* C = fv + which * 272;
      #pragma unroll
      for (int g = 0; g < 16; ++g) {
        float acc = C[256 + g];
        #pragma unroll
        for (int f = 0; f < 16; ++f) acc += h[f] * C[f * 16 + g];
        pkv[wave][which][t * 17 + g] = acc;
      }
    }
  }
  __syncthreads();
  if (lane < WW) {
    const int w = lane;
    const float* P = &pkv[wave][0][0];
    const float* K = &pkv[wave][1][0];
    const float* Vp = &pkv[wave][2][0];
    float kk[4][16];
    #pragma unroll
    for (int m = 0; m < 4; ++m)
      #pragma unroll
      for (int f = 0; f < 16; ++f)
        kk[m][f] = K[(w + m) * 17 + f] + pqg[2176 + m * 544 + v * 16 + f];
    float sc[4][4];
    #pragma unroll
    for (int l = 0; l < 4; ++l) {
      float qv[16];
      #pragma unroll
      for (int i = 0; i < 16; ++i)
        qv[i] = P[(w + l) * 17 + i] + pqg[l * 544 + v * 16 + i];
      #pragma unroll
      for (int m = 0; m < 4; ++m) {
        float s = 0.f;
        #pragma unroll
        for (int i = 0; i < 16; ++i) s += qv[i] * kk[m][i];
        sc[l][m] = s * 0.25f;
      }
    }
    float csum[4] = {0.f, 0.f, 0.f, 0.f};
    #pragma unroll
    for (int l = 0; l < 4; ++l) {
      float mx = fmaxf(fmaxf(sc[l][0], sc[l][1]), fmaxf(sc[l][2], sc[l][3]));
      float sum = 0.f;
      #pragma unroll
      for (int m = 0; m < 4; ++m) { sc[l][m] = expf(sc[l][m] - mx); sum += sc[l][m]; }
      float r = 1.f / sum;
      #pragma unroll
      for (int m = 0; m < 4; ++m) csum[m] += sc[l][m] * r;
    }
    float outv[16];
    #pragma unroll
    for (int f = 0; f < 16; ++f) outv[f] = 0.f;
    #pragma unroll
    for (int m = 0; m < 4; ++m) {
      float c = csum[m];
      #pragma unroll
      for (int f = 0; f < 16; ++f)
        outv[f] += c * (Vp[(w + m) * 17 + f] + pqg[2 * 2176 + m * 544 + v * 16 + f]);
    }
    float4* d4 = (float4*)(ao + ((size_t)(b * VV + v) * WW + w) * 16);
    #pragma unroll
    for (int j = 0; j < 4; ++j)
      d4[j] = make_float4(outv[4*j], outv[4*j+1], outv[4*j+2], outv[4*j+3]);
  }
}

/* ------- message passing + V-axis PE fold; aos slot padded 16->20 floats
   (row stride 240 !== 0 mod 32; lane banks 20*wl+4*q spread ~32 -> <=2-way) ------- */
#define MPW 12
__global__ __launch_bounds__(256) void k_mp(
    const float* __restrict__ ao, const float* __restrict__ adj,
    float* __restrict__ msg2) {
  __shared__ float adjs[VV * VV];
  __shared__ __align__(16) float aos[VV][MPW * 20];
  __shared__ float pes[VV * 16];
  const int bb = blockIdx.x >> 2;
  const int wt = blockIdx.x & 3;
  const int w0 = wt * MPW;
  const int wc = (wt == 3) ? (WW - 3 * MPW) : MPW;
  const int tid = threadIdx.x;
  for (int i = tid; i < VV * VV; i += 256) adjs[i] = adj[i];
  for (int i = tid; i < VV * 16; i += 256) {
    int u = i >> 4, f = i & 15;
    int f2 = f & ~1;
    float dv = expf(-logf(10000.f) * (float)f2 / 16.f);
    float ang = (float)u * dv;
    pes[i] = (f & 1) ? cosf(ang) : sinf(ang);
  }
  const int nq = wc * 4;
  for (int i = tid; i < VV * nq; i += 256) {
    int vv2 = i / nq, r = i - vv2 * nq;
    int wl = r >> 2, q = r & 3;
    float4 val = *(const float4*)(ao + ((size_t)(bb * VV + vv2) * WW + w0 + wl) * 16 + q * 4);
    *(float4*)&aos[vv2][wl * 20 + q * 4] = val;
  }
  __syncthreads();
  for (int i = tid; i < VV * nq; i += 256) {
    int u = i / nq, r = i - u * nq;
    int wl = r >> 2, q = r & 3;
    float a0 = 0.f, a1 = 0.f, a2 = 0.f, a3 = 0.f;
    for (int vv2 = 0; vv2 < VV; ++vv2) {
      float a = adjs[u * VV + vv2];
      float4 s = *(const float4*)&aos[vv2][wl * 20 + q * 4];
      a0 += a * s.x; a1 += a * s.y; a2 += a * s.z; a3 += a * s.w;
    }
    float4 o = make_float4(a0 + pes[u * 16 + q * 4],
                           a1 + pes[u * 16 + q * 4 + 1],
                           a2 + pes[u * 16 + q * 4 + 2],
                           a3 + pes[u * 16 + q * 4 + 3]);
    *(float4*)(msg2 + ((size_t)(bb * VV + u) * WW + w0 + wl) * 16 + q * 4) = o;
  }
}

/* ---------------- signal attention (round-9 sa5): one WAVE per window ---------------- */
__global__ __launch_bounds__(256) void k_sa5(
    const float* __restrict__ msg2, const float* __restrict__ saw,
    const float* __restrict__ wvih, const float* __restrict__ bias2,
    float* __restrict__ xw1) {
  __shared__ __align__(16) float xs[4][VV * 20];   /* 80B rows */
  __shared__ float esc[4][VV * 35];                /* stride 35 */
  __shared__ float wsL[4][VV];
  __shared__ float csL[4][VV];
  __shared__ __align__(16) float ybL[4][16];
  const int tid = threadIdx.x;
  const int g = tid >> 6, lane = tid & 63;
  const int n = blockIdx.x * 4 + g;                /* grid 5888 exact */
  {
    const float4* src = (const float4*)(msg2 + (size_t)blockIdx.x * 4 * 544);
    for (int i = tid; i < 544; i += 256) {
      int gg = i / 136, r = i - gg * 136;
      int m = r >> 2, q = r & 3;
      ((float4*)&xs[gg][m * 20])[q] = src[i];
    }
  }
  __syncthreads();
  float z[16];
  float u = 0.f;
  if (lane < VV) {
    float x[16];
    const float4* xr = (const float4*)&xs[g][lane * 20];
    float4 a0 = xr[0], a1 = xr[1], a2 = xr[2], a3 = xr[3];
    x[0]=a0.x; x[1]=a0.y; x[2]=a0.z; x[3]=a0.w;
    x[4]=a1.x; x[5]=a1.y; x[6]=a1.z; x[7]=a1.w;
    x[8]=a2.x; x[9]=a2.y; x[10]=a2.z; x[11]=a2.w;
    x[12]=a3.x; x[13]=a3.y; x[14]=a3.z; x[15]=a3.w;
    #pragma unroll
    for (int j = 0; j < 16; ++j) {
      float acc = 0.f;
      #pragma unroll
      for (int i = 0; i < 16; ++i) acc += saw[j * 16 + i] * x[i];
      z[j] = acc;
    }
    float w = 0.f;
    #pragma unroll
    for (int i = 0; i < 16; ++i) { u += saw[256 + i] * x[i]; w += saw[272 + i] * x[i]; }
    wsL[g][lane] = w;
  }
  __syncthreads();
  if (lane < VV) {
    const float c0 = saw[288];
    float e[VV];
    #pragma unroll
    for (int m = 0; m < VV; ++m) {
      const float4* xm = (const float4*)&xs[g][m * 20];
      float4 b0 = xm[0], b1 = xm[1], b2 = xm[2], b3 = xm[3];
      float p0 = z[0]*b0.x + z[1]*b0.y + z[2]*b0.z + z[3]*b0.w;
      float p1 = z[4]*b1.x + z[5]*b1.y + z[6]*b1.z + z[7]*b1.w;
      float p2 = z[8]*b2.x + z[9]*b2.y + z[10]*b2.z + z[11]*b2.w;
      float p3 = z[12]*b3.x + z[13]*b3.y + z[14]*b3.z + z[15]*b3.w;
      e[m] = (((p0 + p1) + (p2 + p3)) + u + wsL[g][m] + c0) * 0.25f;
    }
    float mx = e[0];
    #pragma unroll
    for (int m = 1; m < VV; ++m) mx = fmaxf(mx, e[m]);
    float sum = 0.f;
    #pragma unroll
    for (int m = 0; m < VV; ++m) { e[m] = expf(e[m] - mx); sum += e[m]; }
    float rr = 1.f / sum;
    #pragma unroll
    for (int m = 0; m < VV; ++m) esc[g][lane * 35 + m] = e[m] * rr;
  }
  __syncthreads();
  if (lane < VV) {
    float cs = 0.f;
    #pragma unroll
    for (int l = 0; l < VV; ++l) cs += esc[g][l * 35 + lane];
    csL[g][lane] = cs;
  }
  __syncthreads();
  if (lane < 16) {
    float acc = 0.f;
    #pragma unroll
    for (int m = 0; m < VV; ++m) acc += csL[g][m] * xs[g][m * 20 + lane];
    ybL[g][lane] = acc;
  }
  __syncthreads();
  {
    const float4* yr = (const float4*)&ybL[g][0];
    float4 y0 = yr[0], y1 = yr[1], y2 = yr[2], y3 = yr[3];
    float yv[16];
    yv[0]=y0.x; yv[1]=y0.y; yv[2]=y0.z; yv[3]=y0.w;
    yv[4]=y1.x; yv[5]=y1.y; yv[6]=y1.z; yv[7]=y1.w;
    yv[8]=y2.x; yv[9]=y2.y; yv[10]=y2.z; yv[11]=y2.w;
    yv[12]=y3.x; yv[13]=y3.y; yv[14]=y3.z; yv[15]=y3.w;
    #pragma unroll
    for (int k = 0; k < 3; ++k) {
      int o = lane + k * 64;
      float acc = bias2[o];
      #pragma unroll
      for (int i = 0; i < 16; ++i) acc += yv[i] * wvih[i * 192 + o];
      xw1[(size_t)n * 192 + o] = acc;
    }
  }
}

/* ---------------- GRU: weights in VGPRs, readlane h-broadcast, no LDS ---------------- */
__global__ __launch_bounds__(64) void k_gru2(
    const float* __restrict__ xw, const float* __restrict__ Whh,
    const float* __restrict__ bhh, float* __restrict__ gout) {
  const int tid = threadIdx.x;
  const int b = blockIdx.x;
  float wr[64], wz[64], wn[64];
  #pragma unroll
  for (int i = 0; i < 64; ++i) {
    wr[i] = Whh[i * 192 + tid];
    wz[i] = Whh[i * 192 + 64 + tid];
    wn[i] = Whh[i * 192 + 128 + tid];
  }
  const float br = bhh[tid], bz = bhh[64 + tid], bn = bhh[128 + tid];
  float h = 0.f;
  const float* xr = xw + (size_t)b * WW * 192;
  for (int w = 0; w < WW; ++w, xr += 192) {
    float xrv = xr[tid], xzv = xr[64 + tid], xnv = xr[128 + tid];
    float pr0 = br, pr1 = 0.f, pr2 = 0.f, pr3 = 0.f;
    float pz0 = bz, pz1 = 0.f, pz2 = 0.f, pz3 = 0.f;
    float pn0 = bn, pn1 = 0.f, pn2 = 0.f, pn3 = 0.f;
    #pragma unroll
    for (int i = 0; i < 64; i += 4) {
      float h0 = RL(h, i), h1 = RL(h, i + 1), h2 = RL(h, i + 2), h3 = RL(h, i + 3);
      pr0 += h0 * wr[i];     pr1 += h1 * wr[i + 1];
      pr2 += h2 * wr[i + 2]; pr3 += h3 * wr[i + 3];
      pz0 += h0 * wz[i];     pz1 += h1 * wz[i + 1];
      pz2 += h2 * wz[i + 2]; pz3 += h3 * wz[i + 3];
      pn0 += h0 * wn[i];     pn1 += h1 * wn[i + 1];
      pn2 += h2 * wn[i + 2]; pn3 += h3 * wn[i + 3];
    }
    float ar = (pr0 + pr1) + (pr2 + pr3);
    float az = (pz0 + pz1) + (pz2 + pz3);
    float an = (pn0 + pn1) + (pn2 + pn3);
    float r = fsig(xrv + ar);
    float z = fsig(xzv + az);
    float n = ftanh(xnv + r * an);
    h = (1.f - z) * n + z * h;
    gout[((size_t)b * WW + w) * HH + tid] = h;
  }
}

/* ---------------- GRU layer-2 input projection ---------------- */
__global__ __launch_bounds__(192) void k_xw2(
    const float* __restrict__ x, const float* __restrict__ Wih,
    const float* __restrict__ bih, float* __restrict__ xw) {
  __shared__ float xsh[16][HH];
  int n0 = blockIdx.x * 16;
  int tid = threadIdx.x;
  for (int idx = tid; idx < 16 * HH; idx += 192) {
    int ns = idx >> 6, i = idx & 63;
    xsh[ns][i] = x[(size_t)(n0 + ns) * HH + i];
  }
  __syncthreads();
  float acc[16];
  float bb = bih[tid];
  #pragma unroll
  for (int ns = 0; ns < 16; ++ns) acc[ns] = bb;
  for (int i = 0; i < HH; ++i) {
    float wv = Wih[i * TH3 + tid];
    #pragma unroll
    for (int ns = 0; ns < 16; ++ns) acc[ns] += xsh[ns][i] * wv;
  }
  #pragma unroll
  for (int ns = 0; ns < 16; ++ns) xw[(size_t)(n0 + ns) * TH3 + tid] = acc[ns];
}

/* ---------------- temporal attention + classifier ---------------- */
__global__ __launch_bounds__(256) void k_ta(
    const float* __restrict__ g2,
    const float* __restrict__ Wq, const float* __restrict__ bq,
    const float* __restrict__ Wk, const float* __restrict__ bk,
    const float* __restrict__ Wv, const float* __restrict__ bv,
    const float* __restrict__ cW1, const float* __restrict__ cb1,
    const float* __restrict__ cW2, const float* __restrict__ cb2,
    float* __restrict__ out) {
  __shared__ float xt[WW * 65];
  __shared__ float QKVs[3][WW * 65];
  __shared__ float sc[WW * WW];
  __shared__ float cs[WW];
  __shared__ float tval[HH];
  __shared__ float hrelu[HH];
  int tid = threadIdx.x;
  int b = blockIdx.x;
  for (int idx = tid; idx < WW * HH; idx += 256) {
    int w = idx >> 6, d = idx & 63;
    int f2 = d & ~1;
    float dv = expf(-logf(10000.f) * (float)f2 / (float)HH);
    float ang = (float)w * dv;
    float pe = (d & 1) ? cosf(ang) : sinf(ang);
    xt[w * 65 + d] = g2[(size_t)(b * WW + w) * HH + d] + pe;
  }
  __syncthreads();
  if (tid < 192) {
    int which = tid >> 6, d = tid & 63;
    const float* Wt = which == 0 ? Wq : which == 1 ? Wk : Wv;
    float bias = (which == 0 ? bq : which == 1 ? bk : bv)[d];
    float col[HH];
    #pragma unroll
    for (int i = 0; i < HH; ++i) col[i] = Wt[i * HH + d];
    float* dst = &QKVs[which][0];
    for (int w = 0; w < WW; ++w) {
      float acc = bias;
      #pragma unroll
      for (int i = 0; i < HH; ++i) acc += xt[w * 65 + i] * col[i];
      dst[w * 65 + d] = acc;
    }
  }
  __syncthreads();
  for (int idx = tid; idx < WW * WW; idx += 256) {
    int l = idx / WW, m = idx - l * WW;
    float s = 0.f;
    #pragma unroll
    for (int i = 0; i < HH; ++i) s += QKVs[0][l * 65 + i] * QKVs[1][m * 65 + i];
    sc[idx] = s * 0.125f;
  }
  __syncthreads();
  if (tid < WW) {
    float mx = -1e30f;
    for (int m = 0; m < WW; ++m) mx = fmaxf(mx, sc[tid * WW + m]);
    float sum = 0.f;
    for (int m = 0; m < WW; ++m) { float e = expf(sc[tid * WW + m] - mx); sc[tid * WW + m] = e; sum += e; }
    float r = 1.f / sum;
    for (int m = 0; m < WW; ++m) sc[tid * WW + m] *= r;
  }
  __syncthreads();
  if (tid < WW) {
    float s = 0.f;
    for (int l = 0; l < WW; ++l) s += sc[l * WW + tid];
    cs[tid] = s;
  }
  __syncthreads();
  if (tid < HH) {
    float acc = 0.f;
    for (int m = 0; m < WW; ++m) acc += cs[m] * QKVs[2][m * 65 + tid];
    tval[tid] = acc;
  }
  __syncthreads();
  if (tid < HH) {
    float acc = cb1[tid];
    #pragma unroll
    for (int d = 0; d < HH; ++d) acc += tval[d] * cW1[d * HH + tid];
    hrelu[tid] = fmaxf(acc, 0.f);
  }
  __syncthreads();
  if (tid == 0) {
    float acc = cb2[0];
    for (int j = 0; j < HH; ++j) acc += hrelu[j] * cW2[j];
    out[b] = acc;
  }
}

extern "C" void kernel_launch(void* const* d_in, const int* in_sizes, int n_in,
                              void* d_out, int out_size, void* d_ws, size_t ws_size,
                              hipStream_t stream) {
  (void)in_sizes; (void)n_in; (void)out_size; (void)ws_size;
  const float* arr    = (const float*)d_in[0];
  const float* msk    = (const float*)d_in[1];
  const float* timeTB = (const float*)d_in[2];
  const float* wdec   = (const float*)d_in[3];
  const float* bdec   = (const float*)d_in[4];
  const float* encW1  = (const float*)d_in[5];
  const float* encB1  = (const float*)d_in[6];
  const float* encW2  = (const float*)d_in[7];
  const float* encB2  = (const float*)d_in[8];
  const float* tlaWq  = (const float*)d_in[9];
  const float* tlaBq  = (const float*)d_in[10];
  const float* tlaWk  = (const float*)d_in[11];
  const float* tlaBk  = (const float*)d_in[12];
  const float* tlaWv  = (const float*)d_in[13];
  const float* tlaBv  = (const float*)d_in[14];
  const float* adj    = (const float*)d_in[15];
  const float* saWq   = (const float*)d_in[20];
  const float* saBq   = (const float*)d_in[21];
  const float* saWk   = (const float*)d_in[22];
  const float* saBk   = (const float*)d_in[23];
  const float* saWv   = (const float*)d_in[24];
  const float* saBv   = (const float*)d_in[25];
  const float* gWih0  = (const float*)d_in[26];
  const float* gWhh0  = (const float*)d_in[27];
  const float* gBih0  = (const float*)d_in[28];
  const float* gBhh0  = (const float*)d_in[29];
  const float* gWih1  = (const float*)d_in[30];
  const float* gWhh1  = (const float*)d_in[31];
  const float* gBih1  = (const float*)d_in[32];
  const float* gBhh1  = (const float*)d_in[33];
  const float* taWq   = (const float*)d_in[34];
  const float* taBq   = (const float*)d_in[35];
  const float* taWk   = (const float*)d_in[36];
  const float* taBk   = (const float*)d_in[37];
  const float* taWv   = (const float*)d_in[38];
  const float* taBv   = (const float*)d_in[39];
  const float* cW1    = (const float*)d_in[40];
  const float* cb1    = (const float*)d_in[41];
  const float* cW2    = (const float*)d_in[42];
  const float* cb2    = (const float*)d_in[43];
  float* out = (float*)d_out;
  float* ws  = (float*)d_ws;

  float* ao    = ws + AO_OFF;
  float* msg2  = ws + MSG2_OFF;
  float* cum   = ws + CUM2_OFF;
  float* last  = ws + LAST2_OFF;
  float* means = ws + MEANS2_OFF;
  unsigned int* maxv = (unsigned int*)(ws + MAX2_OFF);
  float* pqg   = ws + PQ_OFF;
  float* saw   = ws + SAW_OFF;
  float* fw    = ws + FW_OFF;
  float* wvih  = ws + WVIH_OFF;
  float* bias2 = ws + BIAS2_OFF;

  float* xw1  = ws + XW1_OFF;
  float* g1   = ws + G1_OFF;
  float* xw2  = ws + XW2_OFF;
  float* g2   = ws + G2_OFF;

  hipMemsetAsync(maxv, 0, sizeof(unsigned int), stream);
  k_scan<<<68, 256, 0, stream>>>(arr, msk, timeTB, cum, last, means, maxv);
  k_prep<<<74, 256, 0, stream>>>(tlaWq, tlaWk, tlaWv, tlaBq, tlaBk, tlaBv,
                                 saWq, saBq, saWk, saBk, saWv, saBv,
                                 encW2, encB2, gWih0, gBih0,
                                 pqg, saw, fw, wvih, bias2);
  k_enc4<<<VV * 128, 256, 0, stream>>>(arr, msk, cum, last, means, maxv,
                                       wdec, bdec, encW1, encB1, fw, pqg, ao);
  k_mp<<<BB * 4, 256, 0, stream>>>(ao, adj, msg2);
  k_sa5<<<BW / 4, 256, 0, stream>>>(msg2, saw, wvih, bias2, xw1);
  k_gru2<<<BB, 64, 0, stream>>>(xw1, gWhh0, gBhh0, g1);
  k_xw2<<<BW / 16, 192, 0, stream>>>(g1, gWih1, gBih1, xw2);
  k_gru2<<<BB, 64, 0, stream>>>(xw2, gWhh1, gBhh1, g2);
  k_ta<<<BB, 256, 0, stream>>>(g2, taWq, taBq, taWk, taBk, taWv, taBv,
                               cW1, cb1, cW2, cb2, out);
}

// Round 16
// 338.306 us; speedup vs baseline: 1.0846x; 1.0846x over previous
//
#include <hip/hip_runtime.h>
#include <math.h>

#define BB 512
#define TT 49
#define VV 34
#define FF 16
#define HH 64
#define WW 46
#define BW (BB*WW)        /* 23552 */
#define TH3 (3*HH)        /* 192 */
#define ROWS 25088        /* B*T */

/* GRU-region (offsets in floats) */
#define SOUT_OFF   0ull
#define XW1_OFF    376832ull              /* BW*192 */
#define G1_OFF     (XW1_OFF + 4521984ull)
#define XW2_OFF    (G1_OFF + 1507328ull)
#define G2_OFF     (XW2_OFF + 4521984ull) /* ends 12435456 */

#define MSG_SZ     12812288ull            /* B*V*W*F */
#define CUM_SZ     852992ull              /* B*T*V */
#define MEANS_SZ   17408ull               /* B*V */
#define AO_OFF     12435456ull
#define MSG2_OFF   (AO_OFF + MSG_SZ)      /* 25247744 */
#define CUM2_OFF   (MSG2_OFF + MSG_SZ)
#define LAST2_OFF  (CUM2_OFF + CUM_SZ)
#define MEANS2_OFF (LAST2_OFF + CUM_SZ)
#define MAX2_OFF   (MEANS2_OFF + MEANS_SZ)
#define PQ_OFF     (MAX2_OFF + 4ull)
#define SAW_OFF    (PQ_OFF + 6528ull)
#define FW_OFF     (SAW_OFF + 292ull)     /* 34*816 = 27744 */
#define WVIH_OFF   (FW_OFF + 27744ull)    /* 16*192 = 3072 */
#define BIAS2_OFF  (WVIH_OFF + 3072ull)   /* 192 */

#define RL(x,i) __uint_as_float(__builtin_amdgcn_readlane(__float_as_uint(x), (i)))

/* ---------------- kernel 1: impute scan + global max + means ---------------- */
__global__ __launch_bounds__(256) void k_scan(
    const float* __restrict__ arr, const float* __restrict__ msk,
    const float* __restrict__ timeTB,
    float* __restrict__ cum, float* __restrict__ last,
    float* __restrict__ means, unsigned int* __restrict__ maxv) {
  int tid = blockIdx.x * 256 + threadIdx.x;     /* 0..17407, exact */
  int b = tid / VV, v = tid - b * VV;
  const int base = b * TT * VV + v;
  float x = arr[base];
  float c = 0.f, lm = 0.f, s = x;
  cum[base] = 0.f;
  last[base] = x;
  float tp = timeTB[b];
  for (int t = 1; t < TT; ++t) {
    float tc = timeTB[t * BB + b];
    float d = tc - tp; tp = tc;
    int e = base + t * VV;
    float a = arr[e], m = msk[e];
    float miss = (m == 0.f) ? 1.f : 0.f;
    c = d + c * miss;
    x = (miss > 0.f) ? x : a;
    cum[e] = c; last[e] = x;
    lm = fmaxf(lm, c);
    s += a;
  }
  means[tid] = s * (1.f / 49.f);
  #pragma unroll
  for (int off = 32; off; off >>= 1) lm = fmaxf(lm, __shfl_xor(lm, off));
  if ((threadIdx.x & 63) == 0) atomicMax(maxv, __float_as_uint(lm));
}

/* ---------------- prep: PE proj + SA bilinear + weight folds ---------------- */
__global__ __launch_bounds__(256) void k_prep(
    const float* __restrict__ tlaWq, const float* __restrict__ tlaWk,
    const float* __restrict__ tlaWv,
    const float* __restrict__ tlaBq, const float* __restrict__ tlaBk,
    const float* __restrict__ tlaBv,
    const float* __restrict__ saWq, const float* __restrict__ saBq,
    const float* __restrict__ saWk, const float* __restrict__ saBk,
    const float* __restrict__ saWv, const float* __restrict__ saBv,
    const float* __restrict__ encW2, const float* __restrict__ encB2,
    const float* __restrict__ Wih0, const float* __restrict__ bih0,
    float* __restrict__ pqg, float* __restrict__ saw, float* __restrict__ fw,
    float* __restrict__ wvih, float* __restrict__ bias2) {
  const int bid = blockIdx.x;
  const int t = threadIdx.x;
  if (bid < 26) {
    int idx = bid * 256 + t;
    if (idx >= 6528) return;
    int which = idx / 2176;
    int r = idx - which * 2176;
    int l = r / 544;
    int rr = r - l * 544;
    int v = rr >> 4, f = rr & 15;
    const float* W = which == 0 ? tlaWq : which == 1 ? tlaWk : tlaWv;
    float acc = 0.f;
    #pragma unroll
    for (int i = 0; i < FF; ++i) {
      int i2 = i & ~1;
      float dv = expf(-logf(10000.f) * (float)i2 / (float)FF);
      float ang = (float)l * dv;
      float pe = (i & 1) ? cosf(ang) : sinf(ang);
      acc += pe * W[v * 256 + i * 16 + f];
    }
    pqg[idx] = acc;
  } else if (bid == 26) {
    int i = t & 15, j = t >> 4;
    float a = 0.f;
    #pragma unroll
    for (int f = 0; f < 16; ++f) a += saWq[i * 16 + f] * saWk[j * 16 + f];
    saw[j * 16 + i] = a;                    /* A[i][j] at [j*16+i] */
    if (t < 16) {
      float pp = 0.f, qq = 0.f;
      #pragma unroll
      for (int f = 0; f < 16; ++f) { pp += saWq[t * 16 + f] * saBk[f]; qq += saWk[t * 16 + f] * saBq[f]; }
      saw[256 + t] = pp;
      saw[272 + t] = qq;
    }
    if (t == 0) {
      float c = 0.f;
      #pragma unroll
      for (int f = 0; f < 16; ++f) c += saBq[f] * saBk[f];
      saw[288] = c;
    }
  } else if (bid < 61) {
    const int v = bid - 27;
    const int f = t >> 4, o = t & 15;
    const float* W2v = encW2 + v * 256;
    float cq = 0.f, ck = 0.f, cv = 0.f;
    #pragma unroll
    for (int g = 0; g < 16; ++g) {
      float w2 = W2v[f * 16 + g];
      cq += w2 * tlaWq[v * 256 + g * 16 + o];
      ck += w2 * tlaWk[v * 256 + g * 16 + o];
      cv += w2 * tlaWv[v * 256 + g * 16 + o];
    }
    fw[v * 816 + 0 * 272 + f * 16 + o] = cq;
    fw[v * 816 + 1 * 272 + f * 16 + o] = ck;
    fw[v * 816 + 2 * 272 + f * 16 + o] = cv;
    if (t < 48) {
      int which = t >> 4, o2 = t & 15;
      const float* Wp = which == 0 ? tlaWq : which == 1 ? tlaWk : tlaWv;
      const float* Bp = which == 0 ? tlaBq : which == 1 ? tlaBk : tlaBv;
      float acc = Bp[v * 16 + o2];
      #pragma unroll
      for (int g = 0; g < 16; ++g) acc += encB2[v * 16 + g] * Wp[v * 256 + g * 16 + o2];
      fw[v * 816 + which * 272 + 256 + o2] = acc;
    }
  } else if (bid < 73) {
    int idx = (bid - 61) * 256 + t;          /* < 3072 exact */
    int i = idx / 192, o = idx - i * 192;
    float acc = 0.f;
    #pragma unroll
    for (int f = 0; f < 16; ++f) acc += saWv[i * 16 + f] * Wih0[f * 192 + o];
    wvih[idx] = acc;
  } else {
    if (t < 192) {
      float acc = bih0[t];
      #pragma unroll
      for (int f = 0; f < 16; ++f) acc += 34.f * saBv[f] * Wih0[f * 192 + t];
      bias2[t] = acc;
    }
  }
}

/* ------- fused impute + MLP + folded QKV proj + windowed 4x4 attention -------
   round-9 version: pkv stride 17 (odd -> conflict-free scalar access) */
__global__ __launch_bounds__(256) void k_enc4(
    const float* __restrict__ arr, const float* __restrict__ msk,
    const float* __restrict__ cum, const float* __restrict__ last,
    const float* __restrict__ means, const unsigned int* __restrict__ maxv,
    const float* __restrict__ wdec, const float* __restrict__ bdec,
    const float* __restrict__ W1, const float* __restrict__ B1,
    const float* __restrict__ fw, const float* __restrict__ pqg,
    float* __restrict__ ao) {
  __shared__ float pkv[4][3][TT * 17];
  const int v = blockIdx.x % VV;
  const int bgrp = blockIdx.x / VV;        /* grid = 34*128 */
  const int tid = threadIdx.x;
  const int wave = tid >> 6, lane = tid & 63;
  const int b = bgrp * 4 + wave;
  const float* fv = fw + v * 816;
  if (lane < TT) {
    const int t = lane;
    const int idx = (b * TT + t) * VV + v;
    float inv = 1.f / __uint_as_float(*maxv);
    float a = arr[idx], m = msk[idx];
    float cc = cum[idx] * inv;
    float ttc = fminf(fmaxf(wdec[v] * cc + bdec[v], 0.f), 1000.f);
    float dec = expf(-ttc);
    float xx = a * m + (1.f - m) * (dec * last[idx] + (1.f - dec) * means[b * VV + v]);
    float h[16];
    #pragma unroll
    for (int f = 0; f < 16; ++f)
      h[f] = fmaxf(xx * W1[v * 32 + f] + m * W1[v * 32 + 16 + f] + B1[v * 16 + f], 0.f);
    #pragma unroll
    for (int which = 0; which < 3; ++which) {
      const float* C = fv + which * 272;
      #pragma unroll
      for (int g = 0; g < 16; ++g) {
        float acc = C[256 + g];
        #pragma unroll
        for (int f = 0; f < 16; ++f) acc += h[f] * C[f * 16 + g];
        pkv[wave][which][t * 17 + g] = acc;
      }
    }
  }
  __syncthreads();
  if (lane < WW) {
    const int w = lane;
    const float* P = &pkv[wave][0][0];
    const float* K = &pkv[wave][1][0];
    const float* Vp = &pkv[wave][2][0];
    float kk[4][16];
    #pragma unroll
    for (int m = 0; m < 4; ++m)
      #pragma unroll
      for (int f = 0; f < 16; ++f)
        kk[m][f] = K[(w + m) * 17 + f] + pqg[2176 + m * 544 + v * 16 + f];
    float sc[4][4];
    #pragma unroll
    for (int l = 0; l < 4; ++l) {
      float qv[16];
      #pragma unroll
      for (int i = 0; i < 16; ++i)
        qv[i] = P[(w + l) * 17 + i] + pqg[l * 544 + v * 16 + i];
      #pragma unroll
      for (int m = 0; m < 4; ++m) {
        float s = 0.f;
        #pragma unroll
        for (int i = 0; i < 16; ++i) s += qv[i] * kk[m][i];
        sc[l][m] = s * 0.25f;
      }
    }
    float csum[4] = {0.f, 0.f, 0.f, 0.f};
    #pragma unroll
    for (int l = 0; l < 4; ++l) {
      float mx = fmaxf(fmaxf(sc[l][0], sc[l][1]), fmaxf(sc[l][2], sc[l][3]));
      float sum = 0.f;
      #pragma unroll
      for (int m = 0; m < 4; ++m) { sc[l][m] = expf(sc[l][m] - mx); sum += sc[l][m]; }
      float r = 1.f / sum;
      #pragma unroll
      for (int m = 0; m < 4; ++m) csum[m] += sc[l][m] * r;
    }
    float outv[16];
    #pragma unroll
    for (int f = 0; f < 16; ++f) outv[f] = 0.f;
    #pragma unroll
    for (int m = 0; m < 4; ++m) {
      float c = csum[m];
      #pragma unroll
      for (int f = 0; f < 16; ++f)
        outv[f] += c * (Vp[(w + m) * 17 + f] + pqg[2 * 2176 + m * 544 + v * 16 + f]);
    }
    float4* d4 = (float4*)(ao + ((size_t)(b * VV + v) * WW + w) * 16);
    #pragma unroll
    for (int j = 0; j < 4; ++j)
      d4[j] = make_float4(outv[4*j], outv[4*j+1], outv[4*j+2], outv[4*j+3]);
  }
}

/* ------- message passing + V-axis PE fold, msg2 layout (round-9 version) ------- */
#define MPW 12
__global__ __launch_bounds__(256) void k_mp(
    const float* __restrict__ ao, const float* __restrict__ adj,
    float* __restrict__ msg2) {
  __shared__ float adjs[VV * VV];
  __shared__ __align__(16) float aos[VV][MPW * 16];
  __shared__ float pes[VV * 16];
  const int bb = blockIdx.x >> 2;          /* grid = 512*4 */
  const int wt = blockIdx.x & 3;
  const int w0 = wt * MPW;
  const int wc = (wt == 3) ? (WW - 3 * MPW) : MPW;   /* 12,12,12,10 */
  const int tid = threadIdx.x;
  for (int i = tid; i < VV * VV; i += 256) adjs[i] = adj[i];
  for (int i = tid; i < VV * 16; i += 256) {
    int u = i >> 4, f = i & 15;
    int f2 = f & ~1;
    float dv = expf(-logf(10000.f) * (float)f2 / 16.f);
    float ang = (float)u * dv;
    pes[i] = (f & 1) ? cosf(ang) : sinf(ang);
  }
  const int nq = wc * 4;
  for (int i = tid; i < VV * nq; i += 256) {
    int vv2 = i / nq, r = i - vv2 * nq;
    int wl = r >> 2, q = r & 3;
    float4 val = *(const float4*)(ao + ((size_t)(bb * VV + vv2) * WW + w0 + wl) * 16 + q * 4);
    *(float4*)&aos[vv2][wl * 16 + q * 4] = val;
  }
  __syncthreads();
  for (int i = tid; i < VV * nq; i += 256) {
    int u = i / nq, r = i - u * nq;
    int wl = r >> 2, q = r & 3;
    float a0 = 0.f, a1 = 0.f, a2 = 0.f, a3 = 0.f;
    for (int vv2 = 0; vv2 < VV; ++vv2) {
      float a = adjs[u * VV + vv2];
      float4 s = *(const float4*)&aos[vv2][wl * 16 + q * 4];
      a0 += a * s.x; a1 += a * s.y; a2 += a * s.z; a3 += a * s.w;
    }
    float4 o = make_float4(a0 + pes[u * 16 + q * 4],
                           a1 + pes[u * 16 + q * 4 + 1],
                           a2 + pes[u * 16 + q * 4 + 2],
                           a3 + pes[u * 16 + q * 4 + 3]);
    *(float4*)(msg2 + ((size_t)(bb * VV + u) * WW + w0 + wl) * 16 + q * 4) = o;
  }
}

/* ---------------- signal attention (round-9 sa5): one WAVE per window ----------------
   lane l = row l; x_m via broadcast b128 from LDS; row softmax in registers;
   LDS for staging + colsum transpose. */
__global__ __launch_bounds__(256) void k_sa5(
    const float* __restrict__ msg2, const float* __restrict__ saw,
    const float* __restrict__ wvih, const float* __restrict__ bias2,
    float* __restrict__ xw1) {
  __shared__ __align__(16) float xs[4][VV * 20];   /* 80B rows */
  __shared__ float esc[4][VV * 35];                /* stride 35 */
  __shared__ float wsL[4][VV];
  __shared__ float csL[4][VV];
  __shared__ __align__(16) float ybL[4][16];
  const int tid = threadIdx.x;
  const int g = tid >> 6, lane = tid & 63;
  const int n = blockIdx.x * 4 + g;                /* grid 5888 exact */
  {
    const float4* src = (const float4*)(msg2 + (size_t)blockIdx.x * 4 * 544);
    for (int i = tid; i < 544; i += 256) {
      int gg = i / 136, r = i - gg * 136;
      int m = r >> 2, q = r & 3;
      ((float4*)&xs[gg][m * 20])[q] = src[i];
    }
  }
  __syncthreads();
  float z[16];
  float u = 0.f;
  if (lane < VV) {
    float x[16];
    const float4* xr = (const float4*)&xs[g][lane * 20];
    float4 a0 = xr[0], a1 = xr[1], a2 = xr[2], a3 = xr[3];
    x[0]=a0.x; x[1]=a0.y; x[2]=a0.z; x[3]=a0.w;
    x[4]=a1.x; x[5]=a1.y; x[6]=a1.z; x[7]=a1.w;
    x[8]=a2.x; x[9]=a2.y; x[10]=a2.z; x[11]=a2.w;
    x[12]=a3.x; x[13]=a3.y; x[14]=a3.z; x[15]=a3.w;
    #pragma unroll
    for (int j = 0; j < 16; ++j) {
      float acc = 0.f;
      #pragma unroll
      for (int i = 0; i < 16; ++i) acc += saw[j * 16 + i] * x[i];
      z[j] = acc;
    }
    float w = 0.f;
    #pragma unroll
    for (int i = 0; i < 16; ++i) { u += saw[256 + i] * x[i]; w += saw[272 + i] * x[i]; }
    wsL[g][lane] = w;
  }
  __syncthreads();
  if (lane < VV) {
    const float c0 = saw[288];
    float e[VV];
    #pragma unroll
    for (int m = 0; m < VV; ++m) {
      const float4* xm = (const float4*)&xs[g][m * 20];
      float4 b0 = xm[0], b1 = xm[1], b2 = xm[2], b3 = xm[3];
      float p0 = z[0]*b0.x + z[1]*b0.y + z[2]*b0.z + z[3]*b0.w;
      float p1 = z[4]*b1.x + z[5]*b1.y + z[6]*b1.z + z[7]*b1.w;
      float p2 = z[8]*b2.x + z[9]*b2.y + z[10]*b2.z + z[11]*b2.w;
      float p3 = z[12]*b3.x + z[13]*b3.y + z[14]*b3.z + z[15]*b3.w;
      e[m] = (((p0 + p1) + (p2 + p3)) + u + wsL[g][m] + c0) * 0.25f;
    }
    float mx = e[0];
    #pragma unroll
    for (int m = 1; m < VV; ++m) mx = fmaxf(mx, e[m]);
    float sum = 0.f;
    #pragma unroll
    for (int m = 0; m < VV; ++m) { e[m] = expf(e[m] - mx); sum += e[m]; }
    float rr = 1.f / sum;
    #pragma unroll
    for (int m = 0; m < VV; ++m) esc[g][lane * 35 + m] = e[m] * rr;
  }
  __syncthreads();
  if (lane < VV) {
    float cs = 0.f;
    #pragma unroll
    for (int l = 0; l < VV; ++l) cs += esc[g][l * 35 + lane];
    csL[g][lane] = cs;
  }
  __syncthreads();
  if (lane < 16) {
    float acc = 0.f;
    #pragma unroll
    for (int m = 0; m < VV; ++m) acc += csL[g][m] * xs[g][m * 20 + lane];
    ybL[g][lane] = acc;
  }
  __syncthreads();
  {
    const float4* yr = (const float4*)&ybL[g][0];
    float4 y0 = yr[0], y1 = yr[1], y2 = yr[2], y3 = yr[3];
    float yv[16];
    yv[0]=y0.x; yv[1]=y0.y; yv[2]=y0.z; yv[3]=y0.w;
    yv[4]=y1.x; yv[5]=y1.y; yv[6]=y1.z; yv[7]=y1.w;
    yv[8]=y2.x; yv[9]=y2.y; yv[10]=y2.z; yv[11]=y2.w;
    yv[12]=y3.x; yv[13]=y3.y; yv[14]=y3.z; yv[15]=y3.w;
    #pragma unroll
    for (int k = 0; k < 3; ++k) {
      int o = lane + k * 64;
      float acc = bias2[o];
      #pragma unroll
      for (int i = 0; i < 16; ++i) acc += yv[i] * wvih[i * 192 + o];
      xw1[(size_t)n * 192 + o] = acc;
    }
  }
}

/* ---------------- GRU: weights in 192 VGPRs, readlane h-broadcast, no LDS ---------------- */
__global__ __launch_bounds__(64) void k_gru2(
    const float* __restrict__ xw, const float* __restrict__ Whh,
    const float* __restrict__ bhh, float* __restrict__ gout) {
  const int tid = threadIdx.x;
  const int b = blockIdx.x;
  float wr[64], wz[64], wn[64];
  #pragma unroll
  for (int i = 0; i < 64; ++i) {
    wr[i] = Whh[i * 192 + tid];
    wz[i] = Whh[i * 192 + 64 + tid];
    wn[i] = Whh[i * 192 + 128 + tid];
  }
  const float br = bhh[tid], bz = bhh[64 + tid], bn = bhh[128 + tid];
  float h = 0.f;
  const float* xr = xw + (size_t)b * WW * 192;
  for (int w = 0; w < WW; ++w, xr += 192) {
    float xrv = xr[tid], xzv = xr[64 + tid], xnv = xr[128 + tid];
    float pr0 = br, pr1 = 0.f, pr2 = 0.f, pr3 = 0.f;
    float pz0 = bz, pz1 = 0.f, pz2 = 0.f, pz3 = 0.f;
    float pn0 = bn, pn1 = 0.f, pn2 = 0.f, pn3 = 0.f;
    #pragma unroll
    for (int i = 0; i < 64; i += 4) {
      float h0 = RL(h, i), h1 = RL(h, i + 1), h2 = RL(h, i + 2), h3 = RL(h, i + 3);
      pr0 += h0 * wr[i];     pr1 += h1 * wr[i + 1];
      pr2 += h2 * wr[i + 2]; pr3 += h3 * wr[i + 3];
      pz0 += h0 * wz[i];     pz1 += h1 * wz[i + 1];
      pz2 += h2 * wz[i + 2]; pz3 += h3 * wz[i + 3];
      pn0 += h0 * wn[i];     pn1 += h1 * wn[i + 1];
      pn2 += h2 * wn[i + 2]; pn3 += h3 * wn[i + 3];
    }
    float ar = (pr0 + pr1) + (pr2 + pr3);
    float az = (pz0 + pz1) + (pz2 + pz3);
    float an = (pn0 + pn1) + (pn2 + pn3);
    float r = 1.f / (1.f + expf(-(xrv + ar)));
    float z = 1.f / (1.f + expf(-(xzv + az)));
    float n = tanhf(xnv + r * an);
    h = (1.f - z) * n + z * h;
    gout[((size_t)b * WW + w) * HH + tid] = h;
  }
}

/* ---------------- GRU layer-2 input projection ---------------- */
__global__ __launch_bounds__(192) void k_xw2(
    const float* __restrict__ x, const float* __restrict__ Wih,
    const float* __restrict__ bih, float* __restrict__ xw) {
  __shared__ float xsh[16][HH];
  int n0 = blockIdx.x * 16;
  int tid = threadIdx.x;
  for (int idx = tid; idx < 16 * HH; idx += 192) {
    int ns = idx >> 6, i = idx & 63;
    xsh[ns][i] = x[(size_t)(n0 + ns) * HH + i];
  }
  __syncthreads();
  float acc[16];
  float bb = bih[tid];
  #pragma unroll
  for (int ns = 0; ns < 16; ++ns) acc[ns] = bb;
  for (int i = 0; i < HH; ++i) {
    float wv = Wih[i * TH3 + tid];
    #pragma unroll
    for (int ns = 0; ns < 16; ++ns) acc[ns] += xsh[ns][i] * wv;
  }
  #pragma unroll
  for (int ns = 0; ns < 16; ++ns) xw[(size_t)(n0 + ns) * TH3 + tid] = acc[ns];
}

/* ---------------- temporal attention + classifier ---------------- */
__global__ __launch_bounds__(256) void k_ta(
    const float* __restrict__ g2,
    const float* __restrict__ Wq, const float* __restrict__ bq,
    const float* __restrict__ Wk, const float* __restrict__ bk,
    const float* __restrict__ Wv, const float* __restrict__ bv,
    const float* __restrict__ cW1, const float* __restrict__ cb1,
    const float* __restrict__ cW2, const float* __restrict__ cb2,
    float* __restrict__ out) {
  __shared__ float xt[WW * 65];
  __shared__ float QKVs[3][WW * 65];
  __shared__ float sc[WW * WW];
  __shared__ float cs[WW];
  __shared__ float tval[HH];
  __shared__ float hrelu[HH];
  int tid = threadIdx.x;
  int b = blockIdx.x;
  for (int idx = tid; idx < WW * HH; idx += 256) {
    int w = idx >> 6, d = idx & 63;
    int f2 = d & ~1;
    float dv = expf(-logf(10000.f) * (float)f2 / (float)HH);
    float ang = (float)w * dv;
    float pe = (d & 1) ? cosf(ang) : sinf(ang);
    xt[w * 65 + d] = g2[(size_t)(b * WW + w) * HH + d] + pe;
  }
  __syncthreads();
  if (tid < 192) {
    int which = tid >> 6, d = tid & 63;
    const float* Wt = which == 0 ? Wq : which == 1 ? Wk : Wv;
    float bias = (which == 0 ? bq : which == 1 ? bk : bv)[d];
    float col[HH];
    #pragma unroll
    for (int i = 0; i < HH; ++i) col[i] = Wt[i * HH + d];
    float* dst = &QKVs[which][0];
    for (int w = 0; w < WW; ++w) {
      float acc = bias;
      #pragma unroll
      for (int i = 0; i < HH; ++i) acc += xt[w * 65 + i] * col[i];
      dst[w * 65 + d] = acc;
    }
  }
  __syncthreads();
  for (int idx = tid; idx < WW * WW; idx += 256) {
    int l = idx / WW, m = idx - l * WW;
    float s = 0.f;
    #pragma unroll
    for (int i = 0; i < HH; ++i) s += QKVs[0][l * 65 + i] * QKVs[1][m * 65 + i];
    sc[idx] = s * 0.125f;
  }
  __syncthreads();
  if (tid < WW) {
    float mx = -1e30f;
    for (int m = 0; m < WW; ++m) mx = fmaxf(mx, sc[tid * WW + m]);
    float sum = 0.f;
    for (int m = 0; m < WW; ++m) { float e = expf(sc[tid * WW + m] - mx); sc[tid * WW + m] = e; sum += e; }
    float r = 1.f / sum;
    for (int m = 0; m < WW; ++m) sc[tid * WW + m] *= r;
  }
  __syncthreads();
  if (tid < WW) {
    float s = 0.f;
    for (int l = 0; l < WW; ++l) s += sc[l * WW + tid];
    cs[tid] = s;
  }
  __syncthreads();
  if (tid < HH) {
    float acc = 0.f;
    for (int m = 0; m < WW; ++m) acc += cs[m] * QKVs[2][m * 65 + tid];
    tval[tid] = acc;
  }
  __syncthreads();
  if (tid < HH) {
    float acc = cb1[tid];
    #pragma unroll
    for (int d = 0; d < HH; ++d) acc += tval[d] * cW1[d * HH + tid];
    hrelu[tid] = fmaxf(acc, 0.f);
  }
  __syncthreads();
  if (tid == 0) {
    float acc = cb2[0];
    for (int j = 0; j < HH; ++j) acc += hrelu[j] * cW2[j];
    out[b] = acc;
  }
}

extern "C" void kernel_launch(void* const* d_in, const int* in_sizes, int n_in,
                              void* d_out, int out_size, void* d_ws, size_t ws_size,
                              hipStream_t stream) {
  (void)in_sizes; (void)n_in; (void)out_size; (void)ws_size;
  const float* arr    = (const float*)d_in[0];
  const float* msk    = (const float*)d_in[1];
  const float* timeTB = (const float*)d_in[2];
  const float* wdec   = (const float*)d_in[3];
  const float* bdec   = (const float*)d_in[4];
  const float* encW1  = (const float*)d_in[5];
  const float* encB1  = (const float*)d_in[6];
  const float* encW2  = (const float*)d_in[7];
  const float* encB2  = (const float*)d_in[8];
  const float* tlaWq  = (const float*)d_in[9];
  const float* tlaBq  = (const float*)d_in[10];
  const float* tlaWk  = (const float*)d_in[11];
  const float* tlaBk  = (const float*)d_in[12];
  const float* tlaWv  = (const float*)d_in[13];
  const float* tlaBv  = (const float*)d_in[14];
  const float* adj    = (const float*)d_in[15];
  const float* saWq   = (const float*)d_in[20];
  const float* saBq   = (const float*)d_in[21];
  const float* saWk   = (const float*)d_in[22];
  const float* saBk   = (const float*)d_in[23];
  const float* saWv   = (const float*)d_in[24];
  const float* saBv   = (const float*)d_in[25];
  const float* gWih0  = (const float*)d_in[26];
  const float* gWhh0  = (const float*)d_in[27];
  const float* gBih0  = (const float*)d_in[28];
  const float* gBhh0  = (const float*)d_in[29];
  const float* gWih1  = (const float*)d_in[30];
  const float* gWhh1  = (const float*)d_in[31];
  const float* gBih1  = (const float*)d_in[32];
  const float* gBhh1  = (const float*)d_in[33];
  const float* taWq   = (const float*)d_in[34];
  const float* taBq   = (const float*)d_in[35];
  const float* taWk   = (const float*)d_in[36];
  const float* taBk   = (const float*)d_in[37];
  const float* taWv   = (const float*)d_in[38];
  const float* taBv   = (const float*)d_in[39];
  const float* cW1    = (const float*)d_in[40];
  const float* cb1    = (const float*)d_in[41];
  const float* cW2    = (const float*)d_in[42];
  const float* cb2    = (const float*)d_in[43];
  float* out = (float*)d_out;
  float* ws  = (float*)d_ws;

  float* ao    = ws + AO_OFF;
  float* msg2  = ws + MSG2_OFF;
  float* cum   = ws + CUM2_OFF;
  float* last  = ws + LAST2_OFF;
  float* means = ws + MEANS2_OFF;
  unsigned int* maxv = (unsigned int*)(ws + MAX2_OFF);
  float* pqg   = ws + PQ_OFF;
  float* saw   = ws + SAW_OFF;
  float* fw    = ws + FW_OFF;
  float* wvih  = ws + WVIH_OFF;
  float* bias2 = ws + BIAS2_OFF;

  float* xw1  = ws + XW1_OFF;
  float* g1   = ws + G1_OFF;
  float* xw2  = ws + XW2_OFF;
  float* g2   = ws + G2_OFF;

  hipMemsetAsync(maxv, 0, sizeof(unsigned int), stream);
  k_scan<<<68, 256, 0, stream>>>(arr, msk, timeTB, cum, last, means, maxv);
  k_prep<<<74, 256, 0, stream>>>(tlaWq, tlaWk, tlaWv, tlaBq, tlaBk, tlaBv,
                                 saWq, saBq, saWk, saBk, saWv, saBv,
                                 encW2, encB2, gWih0, gBih0,
                                 pqg, saw, fw, wvih, bias2);
  k_enc4<<<VV * 128, 256, 0, stream>>>(arr, msk, cum, last, means, maxv,
                                       wdec, bdec, encW1, encB1, fw, pqg, ao);
  k_mp<<<BB * 4, 256, 0, stream>>>(ao, adj, msg2);
  k_sa5<<<BW / 4, 256, 0, stream>>>(msg2, saw, wvih, bias2, xw1);
  k_gru2<<<BB, 64, 0, stream>>>(xw1, gWhh0, gBhh0, g1);
  k_xw2<<<BW / 16, 192, 0, stream>>>(g1, gWih1, gBih1, xw2);
  k_gru2<<<BB, 64, 0, stream>>>(xw2, gWhh1, gBhh1, g2);
  k_ta<<<BB, 256, 0, stream>>>(g2, taWq, taBq, taWk, taBk, taWv, taBv,
                               cW1, cb1, cW2, cb2, out);
}